// Round 13
// baseline (137.715 us; speedup 1.0000x reference)
//
#include <hip/hip_runtime.h>
#include <cstdint>

// GCN 2-layer forward on MI355X.
// Layer 1: h = relu((A_hat x) W1 + b1)   -- aggregate at 64ch, then GEMM 64->128
// Layer 2: out = A_hat (h W2) + b2       -- GEMM 128->64 (bf16 out), aggregate 64ch
// CSR-by-dst: init(+x->bf16 split) -> partition (fixed-CAP buckets) ->
// count_scan (LDS degree count + scan + dinv, fused) -> scan_sums ->
// fill_final (add_off + bucket scatter, fused).
// Aggregation r12: channel-split tables (2 x 3.2MB halves, each fits 4MiB
// per-XCD L2) + XCD-partitioned grid (blockIdx%8<4 -> half 0) so each XCD's
// L2 caches only one half. Row 64B, 4 lanes x uint4, 64 nodes/block.
// GEMMs: k-vectorized ds_read_b128 + XOR-swizzled LDS; GEMM2 writes split bf16.

#define IN_C 64
#define HID_C 128
#define OUT_C 64
#define CH 4096   // edges per partition block
#define CAP 8192  // tmp bucket region capacity (mean 4082, uniform input)

__device__ __forceinline__ unsigned short f2bf(float f) {  // RNE
    unsigned int u = __float_as_uint(f);
    return (unsigned short)((u + 0x7FFFu + ((u >> 16) & 1u)) >> 16);
}
__device__ __forceinline__ float bf2f(unsigned int hi16) {  // hi16 in low bits
    return __uint_as_float(hi16 << 16);
}

__device__ __forceinline__ int edge_val(const void* ei, long long idx, int is64) {
    if (is64) return (int)((const long long*)ei)[idx];
    return ((const int*)ei)[idx];
}

// ----- init: detect dtype + x -> split bf16 tables + bucket cursors ----------
__global__ __launch_bounds__(256) void init_conv_k(const unsigned int* __restrict__ ei,
                                                   int* __restrict__ flag,
                                                   int* __restrict__ bcur,
                                                   const float4* __restrict__ x4,
                                                   uint2* __restrict__ xbf0,
                                                   uint2* __restrict__ xbf1, int NC4) {
    int i = blockIdx.x * 256 + threadIdx.x;
    if (i < NC4) {
        float4 v = x4[i];
        uint2 o;
        o.x = (unsigned int)f2bf(v.x) | ((unsigned int)f2bf(v.y) << 16);
        o.y = (unsigned int)f2bf(v.z) | ((unsigned int)f2bf(v.w) << 16);
        int node = i >> 4, chunk = i & 15;  // chunk = 4-channel group
        uint2* dst = (chunk < 8) ? xbf0 : xbf1;
        dst[node * 8 + (chunk & 7)] = o;
    }
    if (blockIdx.x == 0) bcur[threadIdx.x] = threadIdx.x * CAP;
    if (i == 0) {
        int is64 = 1;
#pragma unroll
        for (int k = 0; k < 16; ++k) is64 &= (ei[2 * k + 1] == 0u) ? 1 : 0;
        *flag = is64;  // values < 50000 -> int64 layout has all-zero high dwords
    }
}

// ------ pass 1: partition edges into dst>>8 buckets --------------------------
__global__ __launch_bounds__(256) void partition_k(const void* __restrict__ ei, int E,
                                                   const int* __restrict__ flag,
                                                   int* __restrict__ bcur,
                                                   int2* __restrict__ tmp) {
    __shared__ int2 stage[CH];
    __shared__ int hist[256];
    __shared__ int off[256];
    __shared__ int rcur[256];
    __shared__ int goff[256];
    __shared__ int wsum[4];
    const int tid = threadIdx.x;
    const int base = blockIdx.x * CH;
    const int cnt = min(CH, E - base);
    const int is64 = *flag;
    hist[tid] = 0;
    __syncthreads();
    int sa[16], da[16];
    int ne = 0;
#pragma unroll
    for (int k = 0; k < 16; ++k) {
        int i = tid + k * 256;
        if (i < cnt) {
            sa[ne] = edge_val(ei, base + i, is64);
            da[ne] = edge_val(ei, (long long)E + base + i, is64);
            ne++;
        }
    }
    for (int k = 0; k < ne; ++k) atomicAdd(&hist[da[k] >> 8], 1);
    __syncthreads();
    {  // block-wide exclusive scan of hist -> off
        int v = hist[tid];
        int lane = tid & 63, wid = tid >> 6;
        int s = v;
#pragma unroll
        for (int o = 1; o < 64; o <<= 1) {
            int t = __shfl_up(s, o, 64);
            if (lane >= o) s += t;
        }
        if (lane == 63) wsum[wid] = s;
        __syncthreads();
        int w = 0;
#pragma unroll
        for (int j = 0; j < 4; ++j)
            if (j < wid) w += wsum[j];
        off[tid] = w + s - v;
        rcur[tid] = w + s - v;
    }
    __syncthreads();
    for (int k = 0; k < ne; ++k) {  // stage grouped by bucket
        int b = da[k] >> 8;
        int r = atomicAdd(&rcur[b], 1);
        stage[r] = make_int2(sa[k], da[k]);
    }
    __syncthreads();
    {  // grab space in fixed-capacity bucket region
        int c = hist[tid];
        goff[tid] = (c > 0) ? atomicAdd(&bcur[tid], c) : 0;
    }
    __syncthreads();
    for (int i = tid; i < cnt; i += 256) {  // coalesced-run dump
        int2 e = stage[i];
        int b = e.y >> 8;
        tmp[goff[b] + (i - off[b])] = e;
    }
}

// -- fused: degree count from tmp (LDS) + dinv + block-local exclusive scan ---
__global__ __launch_bounds__(256) void count_scan_k(const int2* __restrict__ tmp,
                                                    const int* __restrict__ bcur,
                                                    int* __restrict__ rowptr,
                                                    float* __restrict__ dinv,
                                                    int* __restrict__ bsum, int n) {
    __shared__ int cnt[256];
    __shared__ int wsum[4];
    const int tid = threadIdx.x;
    const int node0 = blockIdx.x << 8;
    cnt[tid] = 0;
    __syncthreads();
    const int base = blockIdx.x * CAP;
    const int end = bcur[blockIdx.x];
    for (int i = base + tid; i < end; i += 256)
        atomicAdd(&cnt[tmp[i].y - node0], 1);
    __syncthreads();
    const int i = node0 + tid;
    const int lane = tid & 63;
    const int wid = tid >> 6;
    int v = cnt[tid];  // 0 for tid >= nn (no edges target nonexistent nodes)
    if (i < n) dinv[i] = rsqrtf((float)(v + 1));  // +1 self loop
    int s = v;
#pragma unroll
    for (int off = 1; off < 64; off <<= 1) {
        int t = __shfl_up(s, off, 64);
        if (lane >= off) s += t;
    }
    if (lane == 63) wsum[wid] = s;
    __syncthreads();
    int woff = 0;
#pragma unroll
    for (int j = 0; j < 4; ++j)
        if (j < wid) woff += wsum[j];
    if (i < n) rowptr[i] = woff + s - v;  // block-local exclusive
    if (tid == 255) bsum[blockIdx.x] = woff + s;
}

__global__ __launch_bounds__(256) void scan_sums_k(const int* __restrict__ bsum,
                                                   int* __restrict__ boff, int nb) {
    __shared__ int wsum[4];
    const int tid = threadIdx.x;
    const int lane = tid & 63;
    const int wid = tid >> 6;
    int v = (tid < nb) ? bsum[tid] : 0;
    int s = v;
#pragma unroll
    for (int off = 1; off < 64; off <<= 1) {
        int t = __shfl_up(s, off, 64);
        if (lane >= off) s += t;
    }
    if (lane == 63) wsum[wid] = s;
    __syncthreads();
    int woff = 0;
#pragma unroll
    for (int j = 0; j < 4; ++j)
        if (j < wid) woff += wsum[j];
    boff[tid] = woff + s - v;  // exclusive
}

// -- fused: finalize rowptr (+boff) and scatter tmp -> final CSR slots --------
__global__ __launch_bounds__(256) void fill_final_k(const int2* __restrict__ tmp,
                                                    int* __restrict__ rowptr,
                                                    const int* __restrict__ boff,
                                                    const int* __restrict__ bcur,
                                                    const float* __restrict__ dinv,
                                                    int2* __restrict__ edata, int N, int E) {
    __shared__ int cur[256];
    __shared__ float dl[256];
    const int tid = threadIdx.x;
    const int node0 = blockIdx.x << 8;
    const int nn = min(256, N - node0);
    const int bo = boff[blockIdx.x];
    if (tid < nn) {
        int v = rowptr[node0 + tid] + bo;
        rowptr[node0 + tid] = v;  // finalize for aggregation kernels
        cur[tid] = v;
        dl[tid] = dinv[node0 + tid];
    }
    if (blockIdx.x == 0 && tid == 0) rowptr[N] = E;
    __syncthreads();
    const int base = blockIdx.x * CAP;
    const int end = bcur[blockIdx.x];  // base + count
    for (int i = base + tid; i < end; i += 256) {
        int2 e = tmp[i];
        int li = e.y - node0;
        int pos = atomicAdd(&cur[li], 1);
        float wt = dinv[e.x] * dl[li];
        edata[pos] = make_int2(e.x, __float_as_int(wt));
    }
}

// --- aggregation, channel-split: half = (blockIdx%8)>=4 -> XCD-partitioned ---
// 4 lanes x uint4(8 bf16) per 64B row; 64 nodes/block; 4 edges in flight.
template <bool BIAS>
__global__ __launch_bounds__(256) void aggregate_split_k(const uint4* __restrict__ tab0,
                                                         const uint4* __restrict__ tab1,
                                                         const int* __restrict__ rowptr,
                                                         const int2* __restrict__ edata,
                                                         const float* __restrict__ dinv,
                                                         const float4* __restrict__ bias4,
                                                         float4* __restrict__ out4, int N) {
    const int tid = threadIdx.x;
    const int b = blockIdx.x;
    const int g = b >> 3, r = b & 7;
    const int half = (r >> 2) & 1;          // XCDs 0-3 -> half 0, 4-7 -> half 1
    const int sub = g * 4 + (r & 3);        // node-block within half
    const int node = sub * 64 + (tid >> 2);
    const int t = tid & 3;                  // 8 channels per lane
    if (node >= N) return;
    const uint4* __restrict__ tab = half ? tab1 : tab0;
    float dn = dinv[node];
    float sl = dn * dn;
    uint4 sv = tab[(size_t)node * 4 + t];  // self loop row slice (16B)
    float acc[8];
    acc[0] = bf2f(sv.x & 0xFFFF) * sl;
    acc[1] = bf2f(sv.x >> 16) * sl;
    acc[2] = bf2f(sv.y & 0xFFFF) * sl;
    acc[3] = bf2f(sv.y >> 16) * sl;
    acc[4] = bf2f(sv.z & 0xFFFF) * sl;
    acc[5] = bf2f(sv.z >> 16) * sl;
    acc[6] = bf2f(sv.w & 0xFFFF) * sl;
    acc[7] = bf2f(sv.w >> 16) * sl;
    int e = rowptr[node];
    const int e1 = rowptr[node + 1];
#define ACC_EDGE(V, W)                                  \
    acc[0] = fmaf((W), bf2f((V).x & 0xFFFF), acc[0]);   \
    acc[1] = fmaf((W), bf2f((V).x >> 16), acc[1]);      \
    acc[2] = fmaf((W), bf2f((V).y & 0xFFFF), acc[2]);   \
    acc[3] = fmaf((W), bf2f((V).y >> 16), acc[3]);      \
    acc[4] = fmaf((W), bf2f((V).z & 0xFFFF), acc[4]);   \
    acc[5] = fmaf((W), bf2f((V).z >> 16), acc[5]);      \
    acc[6] = fmaf((W), bf2f((V).w & 0xFFFF), acc[6]);   \
    acc[7] = fmaf((W), bf2f((V).w >> 16), acc[7]);
    for (; e + 4 <= e1; e += 4) {
        int2 d0 = edata[e], d1 = edata[e + 1], d2 = edata[e + 2], d3 = edata[e + 3];
        uint4 f0 = tab[(size_t)d0.x * 4 + t];
        uint4 f1 = tab[(size_t)d1.x * 4 + t];
        uint4 f2 = tab[(size_t)d2.x * 4 + t];
        uint4 f3 = tab[(size_t)d3.x * 4 + t];
        ACC_EDGE(f0, __int_as_float(d0.y));
        ACC_EDGE(f1, __int_as_float(d1.y));
        ACC_EDGE(f2, __int_as_float(d2.y));
        ACC_EDGE(f3, __int_as_float(d3.y));
    }
    for (; e < e1; ++e) {
        int2 d0 = edata[e];
        uint4 f0 = tab[(size_t)d0.x * 4 + t];
        ACC_EDGE(f0, __int_as_float(d0.y));
    }
#undef ACC_EDGE
    if (BIAS) {
        float4 b0 = bias4[half * 8 + 2 * t], b1 = bias4[half * 8 + 2 * t + 1];
        acc[0] += b0.x; acc[1] += b0.y; acc[2] += b0.z; acc[3] += b0.w;
        acc[4] += b1.x; acc[5] += b1.y; acc[6] += b1.z; acc[7] += b1.w;
    }
    out4[(size_t)node * 16 + half * 8 + 2 * t] =
        make_float4(acc[0], acc[1], acc[2], acc[3]);
    out4[(size_t)node * 16 + half * 8 + 2 * t + 1] =
        make_float4(acc[4], acc[5], acc[6], acc[7]);
}

// ---- f32 GEMM: C[M,NN] = A[M,K] @ B[K,NN]; k-vectorized, XOR-swizzled -------
// OBF: write bf16 into two split half-tables C (ch<NN/2) and C1 (ch>=NN/2).
template <int K, int NN, int WID, bool RELU, bool OBF>
__global__ __launch_bounds__(256) void gemm_k(const float* __restrict__ A,
                                              const float* __restrict__ B,
                                              const float* __restrict__ bias,
                                              float* __restrict__ C,
                                              float* __restrict__ C1, int M) {
    constexpr int TN = NN / WID;
    constexpr int NR = 256 / WID;
    constexpr int TM = 64 / NR;
    constexpr int K4 = K / 4;
    __shared__ float As[64 * K];
    __shared__ float Bst[NN * K];
    const int tid = threadIdx.x;
    const int row0 = blockIdx.x * 64;

    {  // stage A (row-major, swizzled chunks), coalesced global float4 reads
        const float4* A4 = (const float4*)A;
        for (int i = tid; i < 64 * K4; i += 256) {
            int r = i / K4, c4 = i % K4;
            float4 v = make_float4(0.f, 0.f, 0.f, 0.f);
            if (row0 + r < M) v = A4[(size_t)(row0 + r) * K4 + c4];
            ((float4*)(As + r * K))[c4 ^ (r & 7)] = v;
        }
        // stage B transposed: read B[k][c] float4 coalesced, scatter to BsT
        const float4* B4 = (const float4*)B;
        for (int i = tid; i < K * (NN / 4); i += 256) {
            int k = i / (NN / 4), c4 = i % (NN / 4);
            float4 v = B4[i];
            int c = c4 * 4;
            Bst[(c + 0) * K + (k ^ (((c + 0) & 7) << 2))] = v.x;
            Bst[(c + 1) * K + (k ^ (((c + 1) & 7) << 2))] = v.y;
            Bst[(c + 2) * K + (k ^ (((c + 2) & 7) << 2))] = v.z;
            Bst[(c + 3) * K + (k ^ (((c + 3) & 7) << 2))] = v.w;
        }
    }
    __syncthreads();

    const int rg = tid / WID;   // row group
    const int cgl = tid % WID;  // column lane
    float acc[TM][TN];
#pragma unroll
    for (int i = 0; i < TM; ++i)
#pragma unroll
        for (int j = 0; j < TN; ++j) acc[i][j] = 0.f;

#pragma unroll 4
    for (int k4 = 0; k4 < K4; ++k4) {
        float4 a4[TM], b4[TN];
#pragma unroll
        for (int i = 0; i < TM; ++i) {
            int r = rg * TM + i;
            a4[i] = ((const float4*)(As + r * K))[k4 ^ (r & 7)];
        }
#pragma unroll
        for (int j = 0; j < TN; ++j) {
            int c = cgl + WID * j;
            b4[j] = ((const float4*)(Bst + c * K))[k4 ^ (c & 7)];
        }
#pragma unroll
        for (int i = 0; i < TM; ++i)
#pragma unroll
            for (int j = 0; j < TN; ++j) {
                acc[i][j] = fmaf(a4[i].x, b4[j].x, acc[i][j]);
                acc[i][j] = fmaf(a4[i].y, b4[j].y, acc[i][j]);
                acc[i][j] = fmaf(a4[i].z, b4[j].z, acc[i][j]);
                acc[i][j] = fmaf(a4[i].w, b4[j].w, acc[i][j]);
            }
    }

    float bb[TN];
    if (RELU) {
#pragma unroll
        for (int j = 0; j < TN; ++j) bb[j] = bias[cgl + WID * j];
    }
#pragma unroll
    for (int i = 0; i < TM; ++i) {
        int r = row0 + rg * TM + i;
        if (r < M) {
#pragma unroll
            for (int j = 0; j < TN; ++j) {
                int c = cgl + WID * j;
                float v = acc[i][j];
                if (OBF) {
                    constexpr int HC = NN / 2;
                    unsigned short* dst =
                        (unsigned short*)((c < HC) ? C : C1);
                    dst[(size_t)r * HC + (c & (HC - 1))] = f2bf(v);
                } else {
                    if (RELU) v = fmaxf(v + bb[j], 0.f);
                    C[(size_t)r * NN + c] = v;
                }
            }
        }
    }
}

// ---------------- launch -----------------------------------------------------
extern "C" void kernel_launch(void* const* d_in, const int* in_sizes, int n_in,
                              void* d_out, int out_size, void* d_ws, size_t ws_size,
                              hipStream_t stream) {
    (void)n_in; (void)out_size; (void)ws_size;
    const float* x  = (const float*)d_in[0];
    const void*  ei = d_in[1];
    const float* W1 = (const float*)d_in[2];
    const float* b1 = (const float*)d_in[3];
    const float* W2 = (const float*)d_in[4];
    const float* b2 = (const float*)d_in[5];
    float* out = (float*)d_out;
    const int N = in_sizes[0] / IN_C;   // 50000
    const int E = in_sizes[1] / 2;      // 800000
    const int NB = (N + 255) / 256;     // scan blocks / buckets (196)
    const int PB = (E + CH - 1) / CH;   // partition blocks (196)
    const int NC4 = N * IN_C / 4;       // x float4 count (800000)
    const int NBH = (N + 63) / 64;      // agg node-blocks per half (782)
    const int GRID_AGG = 8 * ((NBH + 3) / 4);  // XCD-partitioned grid (1568)

    char* p = (char*)d_ws;
    auto take = [&](size_t bytes) {
        char* r = p;
        p += (bytes + 255) & ~(size_t)255;
        return r;
    };
    int*   flag    = (int*)take(256);
    int*   rowptr  = (int*)take(((size_t)N + 1) * 4);
    float* dinv    = (float*)take((size_t)N * 4);
    int*   bsum    = (int*)take(1024);
    int*   boff    = (int*)take(1024);
    int*   bcur    = (int*)take(1024);
    int2*  edata   = (int2*)take((size_t)E * 8);
    uint2* xbf0    = (uint2*)take((size_t)N * 64);   // bf16 x, ch 0-31
    uint2* xbf1    = (uint2*)take((size_t)N * 64);   // bf16 x, ch 32-63
    uint2* hwb0    = (uint2*)take((size_t)N * 64);   // bf16 hW2, ch 0-31
    uint2* hwb1    = (uint2*)take((size_t)N * 64);   // bf16 hW2, ch 32-63
    float* agg1    = (float*)take((size_t)N * IN_C * 4);
    float* h       = (float*)take((size_t)N * HID_C * 4);
    // tmp bucket regions: 256*CAP*8B = 16.8MB, alias agg1+h (38.4MB, dead until agg)
    int2*  tmp     = (int2*)agg1;

    init_conv_k<<<(NC4 + 255) / 256, 256, 0, stream>>>(
        (const unsigned int*)ei, flag, bcur, (const float4*)x, xbf0, xbf1, NC4);
    partition_k<<<PB, 256, 0, stream>>>(ei, E, flag, bcur, tmp);
    count_scan_k<<<NB, 256, 0, stream>>>(tmp, bcur, rowptr, dinv, bsum, N);
    scan_sums_k<<<1, 256, 0, stream>>>(bsum, boff, NB);
    fill_final_k<<<NB, 256, 0, stream>>>(tmp, rowptr, boff, bcur, dinv, edata, N, E);

    // layer 1: agg1 = A_hat x (split bf16 gathers); h = relu(agg1 @ W1 + b1)
    aggregate_split_k<false><<<GRID_AGG, 256, 0, stream>>>(
        (const uint4*)xbf0, (const uint4*)xbf1, rowptr, edata, dinv, nullptr,
        (float4*)agg1, N);
    gemm_k<IN_C, HID_C, 32, true, false><<<(N + 63) / 64, 256, 0, stream>>>(
        agg1, W1, b1, h, nullptr, N);

    // layer 2: hwb = bf16(h @ W2) split; out = A_hat hwb + b2
    gemm_k<HID_C, OUT_C, 16, false, true><<<(N + 63) / 64, 256, 0, stream>>>(
        h, W2, nullptr, (float*)hwb0, (float*)hwb1, N);
    aggregate_split_k<true><<<GRID_AGG, 256, 0, stream>>>(
        (const uint4*)hwb0, (const uint4*)hwb1, rowptr, edata, dinv,
        (const float4*)b2, (float4*)out, N);
}

// Round 14
// 136.584 us; speedup vs baseline: 1.0083x; 1.0083x over previous
//
#include <hip/hip_runtime.h>
#include <cstdint>

// GCN 2-layer forward on MI355X.
// Layer 1 (FUSED): h = relu((A_hat x) W1 + b1) in one kernel -- per 64-node
//   block: gather-aggregate into LDS aggs[64][64], then in-block GEMM vs
//   LDS-staged W1^T -> h. Kills the 25.6MB agg1 round-trip + one dispatch.
// Layer 2: hwb = bf16(h @ W2); out = A_hat hwb + b2 (unsplit r12 aggregation;
//   r13's channel-split/XCD partition was a null: +7MB edata re-read, no L2 win).
// CSR-by-dst: init(+x->bf16) -> partition -> count_scan (fused) -> scan_sums
//   -> fill_final (fused).

#define IN_C 64
#define HID_C 128
#define OUT_C 64
#define CH 4096   // edges per partition block
#define CAP 8192  // tmp bucket region capacity (mean 4082, uniform input)

__device__ __forceinline__ unsigned short f2bf(float f) {  // RNE
    unsigned int u = __float_as_uint(f);
    return (unsigned short)((u + 0x7FFFu + ((u >> 16) & 1u)) >> 16);
}
__device__ __forceinline__ float bf2f(unsigned int hi16) {  // hi16 in low bits
    return __uint_as_float(hi16 << 16);
}

__device__ __forceinline__ int edge_val(const void* ei, long long idx, int is64) {
    if (is64) return (int)((const long long*)ei)[idx];
    return ((const int*)ei)[idx];
}

// -------- init: detect dtype + x -> bf16 + bucket cursors --------------------
__global__ __launch_bounds__(256) void init_conv_k(const unsigned int* __restrict__ ei,
                                                   int* __restrict__ flag,
                                                   int* __restrict__ bcur,
                                                   const float4* __restrict__ x4,
                                                   uint2* __restrict__ xbf2, int NC4) {
    int i = blockIdx.x * 256 + threadIdx.x;
    if (i < NC4) {
        float4 v = x4[i];
        uint2 o;
        o.x = (unsigned int)f2bf(v.x) | ((unsigned int)f2bf(v.y) << 16);
        o.y = (unsigned int)f2bf(v.z) | ((unsigned int)f2bf(v.w) << 16);
        xbf2[i] = o;
    }
    if (blockIdx.x == 0) bcur[threadIdx.x] = threadIdx.x * CAP;
    if (i == 0) {
        int is64 = 1;
#pragma unroll
        for (int k = 0; k < 16; ++k) is64 &= (ei[2 * k + 1] == 0u) ? 1 : 0;
        *flag = is64;  // values < 50000 -> int64 layout has all-zero high dwords
    }
}

// ------ pass 1: partition edges into dst>>8 buckets --------------------------
__global__ __launch_bounds__(256) void partition_k(const void* __restrict__ ei, int E,
                                                   const int* __restrict__ flag,
                                                   int* __restrict__ bcur,
                                                   int2* __restrict__ tmp) {
    __shared__ int2 stage[CH];
    __shared__ int hist[256];
    __shared__ int off[256];
    __shared__ int rcur[256];
    __shared__ int goff[256];
    __shared__ int wsum[4];
    const int tid = threadIdx.x;
    const int base = blockIdx.x * CH;
    const int cnt = min(CH, E - base);
    const int is64 = *flag;
    hist[tid] = 0;
    __syncthreads();
    int sa[16], da[16];
    int ne = 0;
#pragma unroll
    for (int k = 0; k < 16; ++k) {
        int i = tid + k * 256;
        if (i < cnt) {
            sa[ne] = edge_val(ei, base + i, is64);
            da[ne] = edge_val(ei, (long long)E + base + i, is64);
            ne++;
        }
    }
    for (int k = 0; k < ne; ++k) atomicAdd(&hist[da[k] >> 8], 1);
    __syncthreads();
    {  // block-wide exclusive scan of hist -> off
        int v = hist[tid];
        int lane = tid & 63, wid = tid >> 6;
        int s = v;
#pragma unroll
        for (int o = 1; o < 64; o <<= 1) {
            int t = __shfl_up(s, o, 64);
            if (lane >= o) s += t;
        }
        if (lane == 63) wsum[wid] = s;
        __syncthreads();
        int w = 0;
#pragma unroll
        for (int j = 0; j < 4; ++j)
            if (j < wid) w += wsum[j];
        off[tid] = w + s - v;
        rcur[tid] = w + s - v;
    }
    __syncthreads();
    for (int k = 0; k < ne; ++k) {  // stage grouped by bucket
        int b = da[k] >> 8;
        int r = atomicAdd(&rcur[b], 1);
        stage[r] = make_int2(sa[k], da[k]);
    }
    __syncthreads();
    {  // grab space in fixed-capacity bucket region
        int c = hist[tid];
        goff[tid] = (c > 0) ? atomicAdd(&bcur[tid], c) : 0;
    }
    __syncthreads();
    for (int i = tid; i < cnt; i += 256) {  // coalesced-run dump
        int2 e = stage[i];
        int b = e.y >> 8;
        tmp[goff[b] + (i - off[b])] = e;
    }
}

// -- fused: degree count from tmp (LDS) + dinv + block-local exclusive scan ---
__global__ __launch_bounds__(256) void count_scan_k(const int2* __restrict__ tmp,
                                                    const int* __restrict__ bcur,
                                                    int* __restrict__ rowptr,
                                                    float* __restrict__ dinv,
                                                    int* __restrict__ bsum, int n) {
    __shared__ int cnt[256];
    __shared__ int wsum[4];
    const int tid = threadIdx.x;
    const int node0 = blockIdx.x << 8;
    cnt[tid] = 0;
    __syncthreads();
    const int base = blockIdx.x * CAP;
    const int end = bcur[blockIdx.x];
    for (int i = base + tid; i < end; i += 256)
        atomicAdd(&cnt[tmp[i].y - node0], 1);
    __syncthreads();
    const int i = node0 + tid;
    const int lane = tid & 63;
    const int wid = tid >> 6;
    int v = cnt[tid];
    if (i < n) dinv[i] = rsqrtf((float)(v + 1));  // +1 self loop
    int s = v;
#pragma unroll
    for (int off = 1; off < 64; off <<= 1) {
        int t = __shfl_up(s, off, 64);
        if (lane >= off) s += t;
    }
    if (lane == 63) wsum[wid] = s;
    __syncthreads();
    int woff = 0;
#pragma unroll
    for (int j = 0; j < 4; ++j)
        if (j < wid) woff += wsum[j];
    if (i < n) rowptr[i] = woff + s - v;  // block-local exclusive
    if (tid == 255) bsum[blockIdx.x] = woff + s;
}

__global__ __launch_bounds__(256) void scan_sums_k(const int* __restrict__ bsum,
                                                   int* __restrict__ boff, int nb) {
    __shared__ int wsum[4];
    const int tid = threadIdx.x;
    const int lane = tid & 63;
    const int wid = tid >> 6;
    int v = (tid < nb) ? bsum[tid] : 0;
    int s = v;
#pragma unroll
    for (int off = 1; off < 64; off <<= 1) {
        int t = __shfl_up(s, off, 64);
        if (lane >= off) s += t;
    }
    if (lane == 63) wsum[wid] = s;
    __syncthreads();
    int woff = 0;
#pragma unroll
    for (int j = 0; j < 4; ++j)
        if (j < wid) woff += wsum[j];
    boff[tid] = woff + s - v;  // exclusive
}

// -- fused: finalize rowptr (+boff) and scatter tmp -> final CSR slots --------
__global__ __launch_bounds__(256) void fill_final_k(const int2* __restrict__ tmp,
                                                    int* __restrict__ rowptr,
                                                    const int* __restrict__ boff,
                                                    const int* __restrict__ bcur,
                                                    const float* __restrict__ dinv,
                                                    int2* __restrict__ edata, int N, int E) {
    __shared__ int cur[256];
    __shared__ float dl[256];
    const int tid = threadIdx.x;
    const int node0 = blockIdx.x << 8;
    const int nn = min(256, N - node0);
    const int bo = boff[blockIdx.x];
    if (tid < nn) {
        int v = rowptr[node0 + tid] + bo;
        rowptr[node0 + tid] = v;  // finalize for aggregation kernels
        cur[tid] = v;
        dl[tid] = dinv[node0 + tid];
    }
    if (blockIdx.x == 0 && tid == 0) rowptr[N] = E;
    __syncthreads();
    const int base = blockIdx.x * CAP;
    const int end = bcur[blockIdx.x];  // base + count
    for (int i = base + tid; i < end; i += 256) {
        int2 e = tmp[i];
        int li = e.y - node0;
        int pos = atomicAdd(&cur[li], 1);
        float wt = dinv[e.x] * dl[li];
        edata[pos] = make_int2(e.x, __float_as_int(wt));
    }
}

// ---- FUSED layer 1: aggregate (bf16 gathers) + GEMM 64->128 + bias + relu ---
// Block = 64 nodes, 256 threads. Phase 1: 8 lanes x uint4 per node row, two
// 32-node sweeps, acc -> LDS aggs[64][64] (float4 chunks XOR-swizzled by row).
// Phase 2: stage W1^T[128][64] swizzled; thread (rg=tid/16, cg=tid%16) computes
// rows rg*4..+3 x cols {cg+16j}, k-vectorized ds_read_b128.
__global__ __launch_bounds__(256) void agg1_gemm1_k(const uint4* __restrict__ feat4,
                                                    const int* __restrict__ rowptr,
                                                    const int2* __restrict__ edata,
                                                    const float* __restrict__ dinv,
                                                    const float* __restrict__ W1,
                                                    const float* __restrict__ b1,
                                                    float* __restrict__ h, int N) {
    __shared__ float aggs[64 * 64];
    __shared__ float W1s[HID_C * 64];  // W1^T, k-chunk swizzled
    const int tid = threadIdx.x;
    const int node0 = blockIdx.x * 64;

    {  // stage W1^T: W1 is [64][128] row-major; scatter transposed+swizzled
        const float4* B4 = (const float4*)W1;
        for (int i = tid; i < 64 * (HID_C / 4); i += 256) {
            int k = i / (HID_C / 4), c4 = i % (HID_C / 4);
            float4 v = B4[i];
            int c = c4 * 4;
            W1s[(c + 0) * 64 + (k ^ (((c + 0) & 7) << 2))] = v.x;
            W1s[(c + 1) * 64 + (k ^ (((c + 1) & 7) << 2))] = v.y;
            W1s[(c + 2) * 64 + (k ^ (((c + 2) & 7) << 2))] = v.z;
            W1s[(c + 3) * 64 + (k ^ (((c + 3) & 7) << 2))] = v.w;
        }
    }

    // phase 1: aggregate 64 nodes (two 32-node sweeps)
    const int t = tid & 7;  // 8 channels per lane: [8t..8t+7]
#pragma unroll
    for (int it = 0; it < 2; ++it) {
        const int rl = it * 32 + (tid >> 3);  // local row 0..63
        const int node = node0 + rl;
        if (node < N) {
            float dn = dinv[node];
            float sl = dn * dn;
            uint4 sv = feat4[(size_t)node * 8 + t];
            float acc[8];
            acc[0] = bf2f(sv.x & 0xFFFF) * sl;
            acc[1] = bf2f(sv.x >> 16) * sl;
            acc[2] = bf2f(sv.y & 0xFFFF) * sl;
            acc[3] = bf2f(sv.y >> 16) * sl;
            acc[4] = bf2f(sv.z & 0xFFFF) * sl;
            acc[5] = bf2f(sv.z >> 16) * sl;
            acc[6] = bf2f(sv.w & 0xFFFF) * sl;
            acc[7] = bf2f(sv.w >> 16) * sl;
            int e = rowptr[node];
            const int e1 = rowptr[node + 1];
#define ACC_EDGE(V, W)                                  \
    acc[0] = fmaf((W), bf2f((V).x & 0xFFFF), acc[0]);   \
    acc[1] = fmaf((W), bf2f((V).x >> 16), acc[1]);      \
    acc[2] = fmaf((W), bf2f((V).y & 0xFFFF), acc[2]);   \
    acc[3] = fmaf((W), bf2f((V).y >> 16), acc[3]);      \
    acc[4] = fmaf((W), bf2f((V).z & 0xFFFF), acc[4]);   \
    acc[5] = fmaf((W), bf2f((V).z >> 16), acc[5]);      \
    acc[6] = fmaf((W), bf2f((V).w & 0xFFFF), acc[6]);   \
    acc[7] = fmaf((W), bf2f((V).w >> 16), acc[7]);
            for (; e + 4 <= e1; e += 4) {
                int2 d0 = edata[e], d1 = edata[e + 1], d2 = edata[e + 2], d3 = edata[e + 3];
                uint4 f0 = feat4[(size_t)d0.x * 8 + t];
                uint4 f1 = feat4[(size_t)d1.x * 8 + t];
                uint4 f2 = feat4[(size_t)d2.x * 8 + t];
                uint4 f3 = feat4[(size_t)d3.x * 8 + t];
                ACC_EDGE(f0, __int_as_float(d0.y));
                ACC_EDGE(f1, __int_as_float(d1.y));
                ACC_EDGE(f2, __int_as_float(d2.y));
                ACC_EDGE(f3, __int_as_float(d3.y));
            }
            for (; e < e1; ++e) {
                int2 d0 = edata[e];
                uint4 f0 = feat4[(size_t)d0.x * 8 + t];
                ACC_EDGE(f0, __int_as_float(d0.y));
            }
#undef ACC_EDGE
            // write 2 swizzled float4 chunks into LDS row rl
            float4* rowp = (float4*)(aggs + rl * 64);
            rowp[(2 * t) ^ (rl & 7)] = make_float4(acc[0], acc[1], acc[2], acc[3]);
            rowp[(2 * t + 1) ^ (rl & 7)] = make_float4(acc[4], acc[5], acc[6], acc[7]);
        }
    }
    __syncthreads();

    // phase 2: h[64][128] = relu(aggs @ W1 + b1)
    const int rg = tid >> 4;   // 0..15 (4 rows each)
    const int cg = tid & 15;   // 0..15 (8 strided cols)
    float acc2[4][8];
#pragma unroll
    for (int i = 0; i < 4; ++i)
#pragma unroll
        for (int j = 0; j < 8; ++j) acc2[i][j] = 0.f;

#pragma unroll 4
    for (int k4 = 0; k4 < 16; ++k4) {
        float4 a4[4], b4[8];
#pragma unroll
        for (int i = 0; i < 4; ++i) {
            int r = rg * 4 + i;
            a4[i] = ((const float4*)(aggs + r * 64))[k4 ^ (r & 7)];
        }
#pragma unroll
        for (int j = 0; j < 8; ++j) {
            int c = cg + 16 * j;
            b4[j] = ((const float4*)(W1s + c * 64))[k4 ^ (c & 7)];
        }
#pragma unroll
        for (int i = 0; i < 4; ++i)
#pragma unroll
            for (int j = 0; j < 8; ++j) {
                acc2[i][j] = fmaf(a4[i].x, b4[j].x, acc2[i][j]);
                acc2[i][j] = fmaf(a4[i].y, b4[j].y, acc2[i][j]);
                acc2[i][j] = fmaf(a4[i].z, b4[j].z, acc2[i][j]);
                acc2[i][j] = fmaf(a4[i].w, b4[j].w, acc2[i][j]);
            }
    }

    float bb[8];
#pragma unroll
    for (int j = 0; j < 8; ++j) bb[j] = b1[cg + 16 * j];
#pragma unroll
    for (int i = 0; i < 4; ++i) {
        int r = node0 + rg * 4 + i;
        if (r < N) {
#pragma unroll
            for (int j = 0; j < 8; ++j) {
                float v = fmaxf(acc2[i][j] + bb[j], 0.f);
                h[(size_t)r * HID_C + cg + 16 * j] = v;
            }
        }
    }
}

// --- aggregation over bf16 table: 8 lanes x uint4(8 bf16) per node, 32/block -
__global__ __launch_bounds__(256) void aggregate_bf16_k(const uint4* __restrict__ feat4,
                                                        const int* __restrict__ rowptr,
                                                        const int2* __restrict__ edata,
                                                        const float* __restrict__ dinv,
                                                        const float4* __restrict__ bias4,
                                                        float4* __restrict__ out4, int N) {
    const int tid = threadIdx.x;
    const int node = blockIdx.x * 32 + (tid >> 3);
    const int t = tid & 7;  // 8 channels per lane
    if (node >= N) return;
    float dn = dinv[node];
    float sl = dn * dn;
    uint4 sv = feat4[(size_t)node * 8 + t];
    float acc[8];
    acc[0] = bf2f(sv.x & 0xFFFF) * sl;
    acc[1] = bf2f(sv.x >> 16) * sl;
    acc[2] = bf2f(sv.y & 0xFFFF) * sl;
    acc[3] = bf2f(sv.y >> 16) * sl;
    acc[4] = bf2f(sv.z & 0xFFFF) * sl;
    acc[5] = bf2f(sv.z >> 16) * sl;
    acc[6] = bf2f(sv.w & 0xFFFF) * sl;
    acc[7] = bf2f(sv.w >> 16) * sl;
    int e = rowptr[node];
    const int e1 = rowptr[node + 1];
#define ACC_EDGE(V, W)                                  \
    acc[0] = fmaf((W), bf2f((V).x & 0xFFFF), acc[0]);   \
    acc[1] = fmaf((W), bf2f((V).x >> 16), acc[1]);      \
    acc[2] = fmaf((W), bf2f((V).y & 0xFFFF), acc[2]);   \
    acc[3] = fmaf((W), bf2f((V).y >> 16), acc[3]);      \
    acc[4] = fmaf((W), bf2f((V).z & 0xFFFF), acc[4]);   \
    acc[5] = fmaf((W), bf2f((V).z >> 16), acc[5]);      \
    acc[6] = fmaf((W), bf2f((V).w & 0xFFFF), acc[6]);   \
    acc[7] = fmaf((W), bf2f((V).w >> 16), acc[7]);
    for (; e + 4 <= e1; e += 4) {
        int2 d0 = edata[e], d1 = edata[e + 1], d2 = edata[e + 2], d3 = edata[e + 3];
        uint4 f0 = feat4[(size_t)d0.x * 8 + t];
        uint4 f1 = feat4[(size_t)d1.x * 8 + t];
        uint4 f2 = feat4[(size_t)d2.x * 8 + t];
        uint4 f3 = feat4[(size_t)d3.x * 8 + t];
        ACC_EDGE(f0, __int_as_float(d0.y));
        ACC_EDGE(f1, __int_as_float(d1.y));
        ACC_EDGE(f2, __int_as_float(d2.y));
        ACC_EDGE(f3, __int_as_float(d3.y));
    }
    for (; e < e1; ++e) {
        int2 d0 = edata[e];
        uint4 f0 = feat4[(size_t)d0.x * 8 + t];
        ACC_EDGE(f0, __int_as_float(d0.y));
    }
#undef ACC_EDGE
    {
        float4 b0 = bias4[2 * t], b1v = bias4[2 * t + 1];
        acc[0] += b0.x; acc[1] += b0.y; acc[2] += b0.z; acc[3] += b0.w;
        acc[4] += b1v.x; acc[5] += b1v.y; acc[6] += b1v.z; acc[7] += b1v.w;
    }
    out4[(size_t)node * 16 + 2 * t] = make_float4(acc[0], acc[1], acc[2], acc[3]);
    out4[(size_t)node * 16 + 2 * t + 1] = make_float4(acc[4], acc[5], acc[6], acc[7]);
}

// ---- f32 GEMM: C[M,NN] = A[M,K] @ B[K,NN]; k-vectorized, XOR-swizzled -------
template <int K, int NN, int WID, bool RELU, bool OBF>
__global__ __launch_bounds__(256) void gemm_k(const float* __restrict__ A,
                                              const float* __restrict__ B,
                                              const float* __restrict__ bias,
                                              float* __restrict__ C, int M) {
    constexpr int TN = NN / WID;
    constexpr int NR = 256 / WID;
    constexpr int TM = 64 / NR;
    constexpr int K4 = K / 4;
    __shared__ float As[64 * K];
    __shared__ float Bst[NN * K];
    const int tid = threadIdx.x;
    const int row0 = blockIdx.x * 64;

    {
        const float4* A4 = (const float4*)A;
        for (int i = tid; i < 64 * K4; i += 256) {
            int r = i / K4, c4 = i % K4;
            float4 v = make_float4(0.f, 0.f, 0.f, 0.f);
            if (row0 + r < M) v = A4[(size_t)(row0 + r) * K4 + c4];
            ((float4*)(As + r * K))[c4 ^ (r & 7)] = v;
        }
        const float4* B4 = (const float4*)B;
        for (int i = tid; i < K * (NN / 4); i += 256) {
            int k = i / (NN / 4), c4 = i % (NN / 4);
            float4 v = B4[i];
            int c = c4 * 4;
            Bst[(c + 0) * K + (k ^ (((c + 0) & 7) << 2))] = v.x;
            Bst[(c + 1) * K + (k ^ (((c + 1) & 7) << 2))] = v.y;
            Bst[(c + 2) * K + (k ^ (((c + 2) & 7) << 2))] = v.z;
            Bst[(c + 3) * K + (k ^ (((c + 3) & 7) << 2))] = v.w;
        }
    }
    __syncthreads();

    const int rg = tid / WID;
    const int cgl = tid % WID;
    float acc[TM][TN];
#pragma unroll
    for (int i = 0; i < TM; ++i)
#pragma unroll
        for (int j = 0; j < TN; ++j) acc[i][j] = 0.f;

#pragma unroll 4
    for (int k4 = 0; k4 < K4; ++k4) {
        float4 a4[TM], b4[TN];
#pragma unroll
        for (int i = 0; i < TM; ++i) {
            int r = rg * TM + i;
            a4[i] = ((const float4*)(As + r * K))[k4 ^ (r & 7)];
        }
#pragma unroll
        for (int j = 0; j < TN; ++j) {
            int c = cgl + WID * j;
            b4[j] = ((const float4*)(Bst + c * K))[k4 ^ (c & 7)];
        }
#pragma unroll
        for (int i = 0; i < TM; ++i)
#pragma unroll
            for (int j = 0; j < TN; ++j) {
                acc[i][j] = fmaf(a4[i].x, b4[j].x, acc[i][j]);
                acc[i][j] = fmaf(a4[i].y, b4[j].y, acc[i][j]);
                acc[i][j] = fmaf(a4[i].z, b4[j].z, acc[i][j]);
                acc[i][j] = fmaf(a4[i].w, b4[j].w, acc[i][j]);
            }
    }

    float bb[TN];
    if (RELU) {
#pragma unroll
        for (int j = 0; j < TN; ++j) bb[j] = bias[cgl + WID * j];
    }
#pragma unroll
    for (int i = 0; i < TM; ++i) {
        int r = row0 + rg * TM + i;
        if (r < M) {
#pragma unroll
            for (int j = 0; j < TN; ++j) {
                int c = cgl + WID * j;
                float v = acc[i][j];
                if (OBF) {
                    ((unsigned short*)C)[(size_t)r * NN + c] = f2bf(v);
                } else {
                    if (RELU) v = fmaxf(v + bb[j], 0.f);
                    C[(size_t)r * NN + c] = v;
                }
            }
        }
    }
}

// ---------------- launch -----------------------------------------------------
extern "C" void kernel_launch(void* const* d_in, const int* in_sizes, int n_in,
                              void* d_out, int out_size, void* d_ws, size_t ws_size,
                              hipStream_t stream) {
    (void)n_in; (void)out_size; (void)ws_size;
    const float* x  = (const float*)d_in[0];
    const void*  ei = d_in[1];
    const float* W1 = (const float*)d_in[2];
    const float* b1 = (const float*)d_in[3];
    const float* W2 = (const float*)d_in[4];
    const float* b2 = (const float*)d_in[5];
    float* out = (float*)d_out;
    const int N = in_sizes[0] / IN_C;   // 50000
    const int E = in_sizes[1] / 2;      // 800000
    const int NB = (N + 255) / 256;     // scan blocks / buckets (196)
    const int PB = (E + CH - 1) / CH;   // partition blocks (196)
    const int NC4 = N * IN_C / 4;       // x float4 count (800000)

    char* p = (char*)d_ws;
    auto take = [&](size_t bytes) {
        char* r = p;
        p += (bytes + 255) & ~(size_t)255;
        return r;
    };
    int*   flag    = (int*)take(256);
    int*   rowptr  = (int*)take(((size_t)N + 1) * 4);
    float* dinv    = (float*)take((size_t)N * 4);
    int*   bsum    = (int*)take(1024);
    int*   boff    = (int*)take(1024);
    int*   bcur    = (int*)take(1024);
    int2*  edata   = (int2*)take((size_t)E * 8);
    uint2* xbf     = (uint2*)take((size_t)N * IN_C * 2);   // bf16 x table
    uint2* hwb     = (uint2*)take((size_t)N * OUT_C * 2);  // bf16 hW2 table
    float* h       = (float*)take((size_t)N * HID_C * 4);
    // tmp bucket regions: 256*CAP*8B = 16.8MB, alias h (25.6MB, dead until agg1_gemm1)
    int2*  tmp     = (int2*)h;

    init_conv_k<<<(NC4 + 255) / 256, 256, 0, stream>>>(
        (const unsigned int*)ei, flag, bcur, (const float4*)x, xbf, NC4);
    partition_k<<<PB, 256, 0, stream>>>(ei, E, flag, bcur, tmp);
    count_scan_k<<<NB, 256, 0, stream>>>(tmp, bcur, rowptr, dinv, bsum, N);
    scan_sums_k<<<1, 256, 0, stream>>>(bsum, boff, NB);
    fill_final_k<<<NB, 256, 0, stream>>>(tmp, rowptr, boff, bcur, dinv, edata, N, E);

    // layer 1 (fused): h = relu((A_hat x) W1 + b1)
    agg1_gemm1_k<<<(N + 63) / 64, 256, 0, stream>>>(
        (const uint4*)xbf, rowptr, edata, dinv, W1, b1, h, N);

    // layer 2: hwb = bf16(h @ W2); out = A_hat hwb + b2
    gemm_k<HID_C, OUT_C, 16, false, true><<<(N + 63) / 64, 256, 0, stream>>>(
        h, W2, nullptr, (float*)hwb, N);
    aggregate_bf16_k<<<(N + 31) / 32, 256, 0, stream>>>(
        (const uint4*)hwb, rowptr, edata, dinv, (const float4*)b2, (float4*)out, N);
}

// Round 15
// 129.103 us; speedup vs baseline: 1.0667x; 1.0579x over previous
//
#include <hip/hip_runtime.h>
#include <cstdint>

// GCN 2-layer forward on MI355X.
// Layer 1: h = relu((A_hat x) W1 + b1)   -- aggregate at 64ch, then GEMM 64->128
// Layer 2: out = A_hat (h W2) + b2       -- GEMM 128->64 (bf16 out), aggregate 64ch
// CSR-by-dst: init(+x->bf16) -> partition (fixed-CAP buckets) -> count_scan
// (LDS degree count + dinv + block scan) -> fill_final (inline 196-sum scan +
// rowptr finalize + bucket scatter). 8 dispatches.
// r14 lesson: agg+GEMM fusion regressed (48KB LDS -> 18% occupancy starved the
// latency-bound gather; W1^T staging had 16-way bank conflicts). Reverted.
// Aggregation: 8 lanes x uint4(8 bf16)/node, 32 nodes/block (1KB/gather-inst).
// GEMMs: k-vectorized ds_read_b128 + XOR-swizzled LDS.

#define IN_C 64
#define HID_C 128
#define OUT_C 64
#define CH 4096   // edges per partition block
#define CAP 8192  // tmp bucket region capacity (mean 4082, uniform input)

__device__ __forceinline__ unsigned short f2bf(float f) {  // RNE
    unsigned int u = __float_as_uint(f);
    return (unsigned short)((u + 0x7FFFu + ((u >> 16) & 1u)) >> 16);
}
__device__ __forceinline__ float bf2f(unsigned int hi16) {  // hi16 in low bits
    return __uint_as_float(hi16 << 16);
}

__device__ __forceinline__ int edge_val(const void* ei, long long idx, int is64) {
    if (is64) return (int)((const long long*)ei)[idx];
    return ((const int*)ei)[idx];
}

// -------- init: detect dtype + x -> bf16 + bucket cursors --------------------
__global__ __launch_bounds__(256) void init_conv_k(const unsigned int* __restrict__ ei,
                                                   int* __restrict__ flag,
                                                   int* __restrict__ bcur,
                                                   const float4* __restrict__ x4,
                                                   uint2* __restrict__ xbf2, int NC4) {
    int i = blockIdx.x * 256 + threadIdx.x;
    if (i < NC4) {
        float4 v = x4[i];
        uint2 o;
        o.x = (unsigned int)f2bf(v.x) | ((unsigned int)f2bf(v.y) << 16);
        o.y = (unsigned int)f2bf(v.z) | ((unsigned int)f2bf(v.w) << 16);
        xbf2[i] = o;
    }
    if (blockIdx.x == 0) bcur[threadIdx.x] = threadIdx.x * CAP;
    if (i == 0) {
        int is64 = 1;
#pragma unroll
        for (int k = 0; k < 16; ++k) is64 &= (ei[2 * k + 1] == 0u) ? 1 : 0;
        *flag = is64;  // values < 50000 -> int64 layout has all-zero high dwords
    }
}

// ------ pass 1: partition edges into dst>>8 buckets --------------------------
__global__ __launch_bounds__(256) void partition_k(const void* __restrict__ ei, int E,
                                                   const int* __restrict__ flag,
                                                   int* __restrict__ bcur,
                                                   int2* __restrict__ tmp) {
    __shared__ int2 stage[CH];
    __shared__ int hist[256];
    __shared__ int off[256];
    __shared__ int rcur[256];
    __shared__ int goff[256];
    __shared__ int wsum[4];
    const int tid = threadIdx.x;
    const int base = blockIdx.x * CH;
    const int cnt = min(CH, E - base);
    const int is64 = *flag;
    hist[tid] = 0;
    __syncthreads();
    int sa[16], da[16];
    int ne = 0;
#pragma unroll
    for (int k = 0; k < 16; ++k) {
        int i = tid + k * 256;
        if (i < cnt) {
            sa[ne] = edge_val(ei, base + i, is64);
            da[ne] = edge_val(ei, (long long)E + base + i, is64);
            ne++;
        }
    }
    for (int k = 0; k < ne; ++k) atomicAdd(&hist[da[k] >> 8], 1);
    __syncthreads();
    {  // block-wide exclusive scan of hist -> off
        int v = hist[tid];
        int lane = tid & 63, wid = tid >> 6;
        int s = v;
#pragma unroll
        for (int o = 1; o < 64; o <<= 1) {
            int t = __shfl_up(s, o, 64);
            if (lane >= o) s += t;
        }
        if (lane == 63) wsum[wid] = s;
        __syncthreads();
        int w = 0;
#pragma unroll
        for (int j = 0; j < 4; ++j)
            if (j < wid) w += wsum[j];
        off[tid] = w + s - v;
        rcur[tid] = w + s - v;
    }
    __syncthreads();
    for (int k = 0; k < ne; ++k) {  // stage grouped by bucket
        int b = da[k] >> 8;
        int r = atomicAdd(&rcur[b], 1);
        stage[r] = make_int2(sa[k], da[k]);
    }
    __syncthreads();
    {  // grab space in fixed-capacity bucket region
        int c = hist[tid];
        goff[tid] = (c > 0) ? atomicAdd(&bcur[tid], c) : 0;
    }
    __syncthreads();
    for (int i = tid; i < cnt; i += 256) {  // coalesced-run dump
        int2 e = stage[i];
        int b = e.y >> 8;
        tmp[goff[b] + (i - off[b])] = e;
    }
}

// -- fused: degree count from tmp (LDS) + dinv + block-local exclusive scan ---
__global__ __launch_bounds__(256) void count_scan_k(const int2* __restrict__ tmp,
                                                    const int* __restrict__ bcur,
                                                    int* __restrict__ rowptr,
                                                    float* __restrict__ dinv,
                                                    int* __restrict__ bsum, int n) {
    __shared__ int cnt[256];
    __shared__ int wsum[4];
    const int tid = threadIdx.x;
    const int node0 = blockIdx.x << 8;
    cnt[tid] = 0;
    __syncthreads();
    const int base = blockIdx.x * CAP;
    const int end = bcur[blockIdx.x];
    for (int i = base + tid; i < end; i += 256)
        atomicAdd(&cnt[tmp[i].y - node0], 1);
    __syncthreads();
    const int i = node0 + tid;
    const int lane = tid & 63;
    const int wid = tid >> 6;
    int v = cnt[tid];
    if (i < n) dinv[i] = rsqrtf((float)(v + 1));  // +1 self loop
    int s = v;
#pragma unroll
    for (int off = 1; off < 64; off <<= 1) {
        int t = __shfl_up(s, off, 64);
        if (lane >= off) s += t;
    }
    if (lane == 63) wsum[wid] = s;
    __syncthreads();
    int woff = 0;
#pragma unroll
    for (int j = 0; j < 4; ++j)
        if (j < wid) woff += wsum[j];
    if (i < n) rowptr[i] = woff + s - v;  // block-local exclusive
    if (tid == 255) bsum[blockIdx.x] = woff + s;
}

// -- fused: inline scan of bsum + finalize rowptr + scatter to CSR slots ------
// (nb <= 256 blocks assumed: N=50000 -> 196)
__global__ __launch_bounds__(256) void fill_final_k(const int2* __restrict__ tmp,
                                                    int* __restrict__ rowptr,
                                                    const int* __restrict__ bsum,
                                                    const int* __restrict__ bcur,
                                                    const float* __restrict__ dinv,
                                                    int2* __restrict__ edata,
                                                    int nb, int N, int E) {
    __shared__ int cur[256];
    __shared__ float dl[256];
    __shared__ int sc[256];
    __shared__ int wsum[4];
    const int tid = threadIdx.x;
    const int node0 = blockIdx.x << 8;
    const int nn = min(256, N - node0);
    {  // inline exclusive scan of bsum -> sc[]
        int v = (tid < nb) ? bsum[tid] : 0;
        int lane = tid & 63, wid = tid >> 6;
        int s = v;
#pragma unroll
        for (int o = 1; o < 64; o <<= 1) {
            int t = __shfl_up(s, o, 64);
            if (lane >= o) s += t;
        }
        if (lane == 63) wsum[wid] = s;
        __syncthreads();
        int w = 0;
#pragma unroll
        for (int j = 0; j < 4; ++j)
            if (j < wid) w += wsum[j];
        sc[tid] = w + s - v;
    }
    __syncthreads();
    const int bo = sc[blockIdx.x];
    if (tid < nn) {
        int v = rowptr[node0 + tid] + bo;
        rowptr[node0 + tid] = v;  // finalize for aggregation kernels
        cur[tid] = v;
        dl[tid] = dinv[node0 + tid];
    }
    if (blockIdx.x == 0 && tid == 0) rowptr[N] = E;
    __syncthreads();
    const int base = blockIdx.x * CAP;
    const int end = bcur[blockIdx.x];  // base + count
    for (int i = base + tid; i < end; i += 256) {
        int2 e = tmp[i];
        int li = e.y - node0;
        int pos = atomicAdd(&cur[li], 1);
        float wt = dinv[e.x] * dl[li];
        edata[pos] = make_int2(e.x, __float_as_int(wt));
    }
}

// --- aggregation over bf16 table: 8 lanes x uint4(8 bf16) per node, 32/block -
template <bool BIAS>
__global__ __launch_bounds__(256) void aggregate_bf16_k(const uint4* __restrict__ feat4,
                                                        const int* __restrict__ rowptr,
                                                        const int2* __restrict__ edata,
                                                        const float* __restrict__ dinv,
                                                        const float4* __restrict__ bias4,
                                                        float4* __restrict__ out4, int N) {
    const int tid = threadIdx.x;
    const int node = blockIdx.x * 32 + (tid >> 3);
    const int t = tid & 7;  // 8 channels per lane: [8t .. 8t+7]
    if (node >= N) return;
    float dn = dinv[node];
    float sl = dn * dn;
    uint4 sv = feat4[(size_t)node * 8 + t];  // self loop row (16B)
    float acc[8];
    acc[0] = bf2f(sv.x & 0xFFFF) * sl;
    acc[1] = bf2f(sv.x >> 16) * sl;
    acc[2] = bf2f(sv.y & 0xFFFF) * sl;
    acc[3] = bf2f(sv.y >> 16) * sl;
    acc[4] = bf2f(sv.z & 0xFFFF) * sl;
    acc[5] = bf2f(sv.z >> 16) * sl;
    acc[6] = bf2f(sv.w & 0xFFFF) * sl;
    acc[7] = bf2f(sv.w >> 16) * sl;
    int e = rowptr[node];
    const int e1 = rowptr[node + 1];
#define ACC_EDGE(V, W)                                  \
    acc[0] = fmaf((W), bf2f((V).x & 0xFFFF), acc[0]);   \
    acc[1] = fmaf((W), bf2f((V).x >> 16), acc[1]);      \
    acc[2] = fmaf((W), bf2f((V).y & 0xFFFF), acc[2]);   \
    acc[3] = fmaf((W), bf2f((V).y >> 16), acc[3]);      \
    acc[4] = fmaf((W), bf2f((V).z & 0xFFFF), acc[4]);   \
    acc[5] = fmaf((W), bf2f((V).z >> 16), acc[5]);      \
    acc[6] = fmaf((W), bf2f((V).w & 0xFFFF), acc[6]);   \
    acc[7] = fmaf((W), bf2f((V).w >> 16), acc[7]);
    for (; e + 4 <= e1; e += 4) {  // 4 x 1KB gathers in flight per wave
        int2 d0 = edata[e], d1 = edata[e + 1], d2 = edata[e + 2], d3 = edata[e + 3];
        uint4 f0 = feat4[(size_t)d0.x * 8 + t];
        uint4 f1 = feat4[(size_t)d1.x * 8 + t];
        uint4 f2 = feat4[(size_t)d2.x * 8 + t];
        uint4 f3 = feat4[(size_t)d3.x * 8 + t];
        ACC_EDGE(f0, __int_as_float(d0.y));
        ACC_EDGE(f1, __int_as_float(d1.y));
        ACC_EDGE(f2, __int_as_float(d2.y));
        ACC_EDGE(f3, __int_as_float(d3.y));
    }
    for (; e < e1; ++e) {
        int2 d0 = edata[e];
        uint4 f0 = feat4[(size_t)d0.x * 8 + t];
        ACC_EDGE(f0, __int_as_float(d0.y));
    }
#undef ACC_EDGE
    if (BIAS) {
        float4 b0 = bias4[2 * t], b1v = bias4[2 * t + 1];
        acc[0] += b0.x; acc[1] += b0.y; acc[2] += b0.z; acc[3] += b0.w;
        acc[4] += b1v.x; acc[5] += b1v.y; acc[6] += b1v.z; acc[7] += b1v.w;
    }
    out4[(size_t)node * 16 + 2 * t] = make_float4(acc[0], acc[1], acc[2], acc[3]);
    out4[(size_t)node * 16 + 2 * t + 1] = make_float4(acc[4], acc[5], acc[6], acc[7]);
}

// ---- f32 GEMM: C[M,NN] = A[M,K] @ B[K,NN]; k-vectorized, XOR-swizzled -------
template <int K, int NN, int WID, bool RELU, bool OBF>
__global__ __launch_bounds__(256) void gemm_k(const float* __restrict__ A,
                                              const float* __restrict__ B,
                                              const float* __restrict__ bias,
                                              float* __restrict__ C, int M) {
    constexpr int TN = NN / WID;
    constexpr int NR = 256 / WID;
    constexpr int TM = 64 / NR;
    constexpr int K4 = K / 4;
    __shared__ float As[64 * K];
    __shared__ float Bst[NN * K];
    const int tid = threadIdx.x;
    const int row0 = blockIdx.x * 64;

    {  // stage A (row-major, swizzled chunks), coalesced global float4 reads
        const float4* A4 = (const float4*)A;
        for (int i = tid; i < 64 * K4; i += 256) {
            int r = i / K4, c4 = i % K4;
            float4 v = make_float4(0.f, 0.f, 0.f, 0.f);
            if (row0 + r < M) v = A4[(size_t)(row0 + r) * K4 + c4];
            ((float4*)(As + r * K))[c4 ^ (r & 7)] = v;
        }
        // stage B transposed: read B[k][c] float4 coalesced, scatter to BsT
        const float4* B4 = (const float4*)B;
        for (int i = tid; i < K * (NN / 4); i += 256) {
            int k = i / (NN / 4), c4 = i % (NN / 4);
            float4 v = B4[i];
            int c = c4 * 4;
            Bst[(c + 0) * K + (k ^ (((c + 0) & 7) << 2))] = v.x;
            Bst[(c + 1) * K + (k ^ (((c + 1) & 7) << 2))] = v.y;
            Bst[(c + 2) * K + (k ^ (((c + 2) & 7) << 2))] = v.z;
            Bst[(c + 3) * K + (k ^ (((c + 3) & 7) << 2))] = v.w;
        }
    }
    __syncthreads();

    const int rg = tid / WID;   // row group
    const int cgl = tid % WID;  // column lane
    float acc[TM][TN];
#pragma unroll
    for (int i = 0; i < TM; ++i)
#pragma unroll
        for (int j = 0; j < TN; ++j) acc[i][j] = 0.f;

#pragma unroll 4
    for (int k4 = 0; k4 < K4; ++k4) {
        float4 a4[TM], b4[TN];
#pragma unroll
        for (int i = 0; i < TM; ++i) {
            int r = rg * TM + i;
            a4[i] = ((const float4*)(As + r * K))[k4 ^ (r & 7)];
        }
#pragma unroll
        for (int j = 0; j < TN; ++j) {
            int c = cgl + WID * j;
            b4[j] = ((const float4*)(Bst + c * K))[k4 ^ (c & 7)];
        }
#pragma unroll
        for (int i = 0; i < TM; ++i)
#pragma unroll
            for (int j = 0; j < TN; ++j) {
                acc[i][j] = fmaf(a4[i].x, b4[j].x, acc[i][j]);
                acc[i][j] = fmaf(a4[i].y, b4[j].y, acc[i][j]);
                acc[i][j] = fmaf(a4[i].z, b4[j].z, acc[i][j]);
                acc[i][j] = fmaf(a4[i].w, b4[j].w, acc[i][j]);
            }
    }

    float bb[TN];
    if (RELU) {
#pragma unroll
        for (int j = 0; j < TN; ++j) bb[j] = bias[cgl + WID * j];
    }
#pragma unroll
    for (int i = 0; i < TM; ++i) {
        int r = row0 + rg * TM + i;
        if (r < M) {
#pragma unroll
            for (int j = 0; j < TN; ++j) {
                int c = cgl + WID * j;
                float v = acc[i][j];
                if (OBF) {
                    ((unsigned short*)C)[(size_t)r * NN + c] = f2bf(v);
                } else {
                    if (RELU) v = fmaxf(v + bb[j], 0.f);
                    C[(size_t)r * NN + c] = v;
                }
            }
        }
    }
}

// ---------------- launch -----------------------------------------------------
extern "C" void kernel_launch(void* const* d_in, const int* in_sizes, int n_in,
                              void* d_out, int out_size, void* d_ws, size_t ws_size,
                              hipStream_t stream) {
    (void)n_in; (void)out_size; (void)ws_size;
    const float* x  = (const float*)d_in[0];
    const void*  ei = d_in[1];
    const float* W1 = (const float*)d_in[2];
    const float* b1 = (const float*)d_in[3];
    const float* W2 = (const float*)d_in[4];
    const float* b2 = (const float*)d_in[5];
    float* out = (float*)d_out;
    const int N = in_sizes[0] / IN_C;   // 50000
    const int E = in_sizes[1] / 2;      // 800000
    const int NB = (N + 255) / 256;     // scan blocks / buckets (196)
    const int PB = (E + CH - 1) / CH;   // partition blocks (196)
    const int NC4 = N * IN_C / 4;       // x float4 count (800000)

    char* p = (char*)d_ws;
    auto take = [&](size_t bytes) {
        char* r = p;
        p += (bytes + 255) & ~(size_t)255;
        return r;
    };
    int*   flag    = (int*)take(256);
    int*   rowptr  = (int*)take(((size_t)N + 1) * 4);
    float* dinv    = (float*)take((size_t)N * 4);
    int*   bsum    = (int*)take(1024);
    int*   bcur    = (int*)take(1024);
    int2*  edata   = (int2*)take((size_t)E * 8);
    uint2* xbf     = (uint2*)take((size_t)N * IN_C * 2);   // bf16 x table
    uint2* hwb     = (uint2*)take((size_t)N * OUT_C * 2);  // bf16 hW2 table
    float* agg1    = (float*)take((size_t)N * IN_C * 4);
    float* h       = (float*)take((size_t)N * HID_C * 4);
    // tmp bucket regions: 256*CAP*8B = 16.8MB, alias agg1+h (38.4MB, dead until agg)
    int2*  tmp     = (int2*)agg1;

    init_conv_k<<<(NC4 + 255) / 256, 256, 0, stream>>>(
        (const unsigned int*)ei, flag, bcur, (const float4*)x, xbf, NC4);
    partition_k<<<PB, 256, 0, stream>>>(ei, E, flag, bcur, tmp);
    count_scan_k<<<NB, 256, 0, stream>>>(tmp, bcur, rowptr, dinv, bsum, N);
    fill_final_k<<<NB, 256, 0, stream>>>(tmp, rowptr, bsum, bcur, dinv, edata, NB, N, E);

    // layer 1: agg1 = A_hat x (bf16 gathers); h = relu(agg1 @ W1 + b1)
    aggregate_bf16_k<false><<<(N + 31) / 32, 256, 0, stream>>>(
        (const uint4*)xbf, rowptr, edata, dinv, nullptr, (float4*)agg1, N);
    gemm_k<IN_C, HID_C, 32, true, false><<<(N + 63) / 64, 256, 0, stream>>>(
        agg1, W1, b1, h, N);

    // layer 2: hwb = bf16(h @ W2); out = A_hat hwb + b2
    gemm_k<HID_C, OUT_C, 16, false, true><<<(N + 63) / 64, 256, 0, stream>>>(
        h, W2, nullptr, (float*)hwb, N);
    aggregate_bf16_k<true><<<(N + 31) / 32, 256, 0, stream>>>(
        (const uint4*)hwb, rowptr, edata, dinv, (const float4*)b2, (float4*)out, N);
}